// Round 18
// baseline (86.003 us; speedup 1.0000x reference)
//
#include <hip/hip_runtime.h>
#include <hip/hip_bf16.h>

#define PROJ 128
#define KPAD 192
#define EPS 1e-5f
#define CVALID 40

typedef __attribute__((ext_vector_type(4))) float f32x4;
typedef __attribute__((ext_vector_type(8))) short bf16x8;
typedef __attribute__((ext_vector_type(4))) unsigned int u32x4;

__device__ inline float bflo(unsigned u){ union{unsigned x;float f;}c; c.x = u<<16; return c.f; }
__device__ inline float bfhi(unsigned u){ union{unsigned x;float f;}c; c.x = u & 0xffff0000u; return c.f; }
__device__ inline float bf2f(unsigned short u){ union{unsigned x;float f;}c; c.x = ((unsigned)u)<<16; return c.f; }
__device__ inline unsigned short f2bf(float f){
    union{float f; unsigned u;} c; c.f = f;
    unsigned r = c.u + 0x7fff + ((c.u >> 16) & 1);
    return (unsigned short)(r >> 16);
}
__device__ __forceinline__ bf16x8 asbf(u32x4 u){ union{u32x4 a; bf16x8 b;} c; c.a = u; return c.b; }
__device__ __forceinline__ unsigned pk2(float a, float b){
    return (unsigned)f2bf(a) | ((unsigned)f2bf(b) << 16);
}

// ================= prep (x8 vectorized): conversion/packing + src + combined bias ==
__global__ __launch_bounds__(256) void prep_all(
    const float* __restrict__ W_proj, const float* __restrict__ Wq,
    const float* __restrict__ Wk, const float* __restrict__ Wv,
    const float* __restrict__ Wo, const float* __restrict__ Ws,
    const float* __restrict__ convw, const float* __restrict__ input,
    const float* __restrict__ bq, const float* __restrict__ b_proj,
    unsigned short* __restrict__ Wqb, unsigned short* __restrict__ Wkb,
    unsigned short* __restrict__ Wvb, unsigned short* __restrict__ Wob,
    unsigned short* __restrict__ Wsb, unsigned short* __restrict__ Wcb,
    unsigned short* __restrict__ WpbT, unsigned short* __restrict__ srcb,
    float* __restrict__ zbias, float* __restrict__ bqc, int L)
{
    int idx = blockIdx.x * 256 + threadIdx.x;
    if (idx < 81920) {
        int w = idx >> 6, lanei = idx & 63;
        int r = w >> 8, o = w & 255;
        const float* wrow = Wq + (size_t)o * 256;
        const float* bp = b_proj + r * 256;
        float s = 0.f;
        #pragma unroll
        for (int c = 0; c < 256; c += 64) s += wrow[c + lanei] * bp[c + lanei];
        #pragma unroll
        for (int m = 32; m > 0; m >>= 1) s += __shfl_xor(s, m, 64);
        if (lanei == 0) bqc[w] = s + bq[o];
        return;
    }
    idx -= 81920;
    if (idx < 8192) {        // Wqb copy x8
        const float* s = Wq + (size_t)idx * 8;
        *(u32x4*)&Wqb[(size_t)idx * 8] =
            (u32x4){pk2(s[0],s[1]), pk2(s[2],s[3]), pk2(s[4],s[5]), pk2(s[6],s[7])};
        return;
    }
    idx -= 8192;
    if (idx < 12288) {       // Wkb / Wvb x8
        int which = idx / 6144, t = idx % 6144;
        int r = t / 24, c0 = (t % 24) * 8;
        const float* W = which ? Wv : Wk;
        unsigned short* D = which ? Wvb : Wkb;
        u32x4 v = {0,0,0,0};
        if (c0 < 136) {
            const float* s = W + (size_t)r * 136 + c0;
            v = (u32x4){pk2(s[0],s[1]), pk2(s[2],s[3]), pk2(s[4],s[5]), pk2(s[6],s[7])};
        }
        *(u32x4*)&D[(size_t)r * 192 + c0] = v;
        return;
    }
    idx -= 12288;
    if (idx < 16384) {       // Wob / Wsb fragment-packed x8 (kt in [0,4))
        int which = idx / 8192, t = idx % 8192;
        int lane = t & 63, fr = (t >> 6) & 3, wid = (t >> 8) & 7, kt = t >> 11;
        int o = wid * 32 + (fr >> 1) * 16 + (lane & 15);
        int c = kt * 64 + (fr & 1) * 32 + (lane >> 4) * 8;
        const float* s = (which ? Ws : Wo) + (size_t)o * 256 + c;
        unsigned short* D = which ? Wsb : Wob;
        *(u32x4*)&D[(size_t)t * 8] =
            (u32x4){pk2(s[0],s[1]), pk2(s[2],s[3]), pk2(s[4],s[5]), pk2(s[6],s[7])};
        return;
    }
    idx -= 16384;
    if (idx < 98304) {       // Wcb fragment-packed x8 (ktl = l*12+kt)
        int t = idx;
        int lane = t & 63, fr = (t >> 6) & 3, wid = (t >> 8) & 7, ktl = t >> 11;
        int l = ktl / 12, kt = ktl % 12;
        int o = wid * 32 + (fr >> 1) * 16 + (lane & 15);
        int c = kt * 64 + (fr & 1) * 32 + (lane >> 4) * 8;
        int ktap = c >> 8, ci = c & 255;
        const float* s = convw + (((size_t)l * 256 + o) * 256 + ci) * 3 + ktap;
        float v[8];
        #pragma unroll
        for (int j = 0; j < 8; ++j) v[j] = s[(size_t)j * 3];
        *(u32x4*)&Wcb[(size_t)t * 8] =
            (u32x4){pk2(v[0],v[1]), pk2(v[2],v[3]), pk2(v[4],v[5]), pk2(v[6],v[7])};
        return;
    }
    idx -= 98304;
    if (idx < 40960) {       // WpbT x8 over d
        int t = idx;
        int r = t >> 13;
        int c = (t >> 5) & 255;
        int d0 = (t & 31) * 8;
        u32x4 v = {0,0,0,0};
        if (c < 136) {
            const float* s = W_proj + ((size_t)(r * 256 + d0)) * 136 + c;
            float x[8];
            #pragma unroll
            for (int j = 0; j < 8; ++j) x[j] = s[(size_t)j * 136];
            v = (u32x4){pk2(x[0],x[1]), pk2(x[2],x[3]), pk2(x[4],x[5]), pk2(x[6],x[7])};
        }
        *(u32x4*)&WpbT[(size_t)t * 8] = v;
        return;
    }
    idx -= 40960;
    if (idx < L * 24) {      // srcb x8
        int n = idx / 24, c0 = (idx % 24) * 8;
        u32x4 v = {0,0,0,0};
        if (c0 < PROJ) {
            const float* s = input + (size_t)n * PROJ + c0;
            v = (u32x4){pk2(s[0],s[1]), pk2(s[2],s[3]), pk2(s[4],s[5]), pk2(s[6],s[7])};
        } else if (c0 == PROJ) {
            float p[8];
            #pragma unroll
            for (int i = 0; i < 8; ++i) {
                int mask = (2 << i) - 1;
                p[i] = (float)(n & mask) / (float)(1 << i);
            }
            v = (u32x4){pk2(p[0],p[1]), pk2(p[2],p[3]), pk2(p[4],p[5]), pk2(p[6],p[7])};
        }
        *(u32x4*)&srcb[(size_t)n * KPAD + c0] = v;
        return;
    }
    idx -= L * 24;
    if (idx < 256) { zbias[idx] = 0.f; return; }
}

// ================= shared 64x128 GEMM core =================
__device__ __forceinline__ void gemm_core_64x128(
    unsigned short (&As)[64][72], unsigned short (&Bs)[128][72],
    const unsigned short* __restrict__ A, int lda,
    const unsigned short* __restrict__ B, int ldb,
    const float* __restrict__ bias,
    unsigned short* __restrict__ C, int ldc,
    int K, int m0, int n0)
{
    const int tid = threadIdx.x;
    const int lane = tid & 63;
    const int wid = tid >> 6;
    const int wm = wid >> 1, wn = wid & 1;

    const int ar = tid >> 2, asg = tid & 3;
    const int br = tid >> 1, bsg = tid & 1;

    const unsigned short* Ap = A + (size_t)(m0 + ar) * lda + asg * 16;
    const unsigned short* Bp = B + (size_t)(n0 + br) * ldb + bsg * 32;

    u32x4 ra0, ra1, rb0, rb1, rb2, rb3;
    auto loadregs = [&](int k0) {
        ra0 = *(const u32x4*)(Ap + k0);
        ra1 = *(const u32x4*)(Ap + k0 + 8);
        rb0 = *(const u32x4*)(Bp + k0);
        rb1 = *(const u32x4*)(Bp + k0 + 8);
        rb2 = *(const u32x4*)(Bp + k0 + 16);
        rb3 = *(const u32x4*)(Bp + k0 + 24);
    };
    auto stlds = [&]() {
        *(u32x4*)&As[ar][asg * 16]      = ra0;
        *(u32x4*)&As[ar][asg * 16 + 8]  = ra1;
        *(u32x4*)&Bs[br][bsg * 32]      = rb0;
        *(u32x4*)&Bs[br][bsg * 32 + 8]  = rb1;
        *(u32x4*)&Bs[br][bsg * 32 + 16] = rb2;
        *(u32x4*)&Bs[br][bsg * 32 + 24] = rb3;
    };

    f32x4 acc[2][4];
    #pragma unroll
    for (int i = 0; i < 2; ++i)
        #pragma unroll
        for (int j = 0; j < 4; ++j) acc[i][j] = (f32x4){0.f, 0.f, 0.f, 0.f};

    loadregs(0);
    stlds();
    __syncthreads();

    const int rowf = lane & 15, kb = lane >> 4;
    const int ktiles = K >> 6;
    for (int kt = 0; kt < ktiles; ++kt) {
        if (kt + 1 < ktiles) loadregs((kt + 1) << 6);
        #pragma unroll
        for (int ks = 0; ks < 2; ++ks) {
            bf16x8 af[2], bfr[4];
            #pragma unroll
            for (int i = 0; i < 2; ++i)
                af[i] = *(const bf16x8*)&As[wm * 32 + i * 16 + rowf][ks * 32 + kb * 8];
            #pragma unroll
            for (int j = 0; j < 4; ++j)
                bfr[j] = *(const bf16x8*)&Bs[wn * 64 + j * 16 + rowf][ks * 32 + kb * 8];
            #pragma unroll
            for (int i = 0; i < 2; ++i)
                #pragma unroll
                for (int j = 0; j < 4; ++j)
                    acc[i][j] = __builtin_amdgcn_mfma_f32_16x16x32_bf16(af[i], bfr[j], acc[i][j], 0, 0, 0);
        }
        __syncthreads();
        if (kt + 1 < ktiles) { stlds(); __syncthreads(); }
    }

    const int rq = lane >> 4;
    #pragma unroll
    for (int i = 0; i < 2; ++i) {
        int gm = m0 + wm * 32 + i * 16 + rq * 4;
        #pragma unroll
        for (int j = 0; j < 4; ++j) {
            int gn = n0 + wn * 64 + j * 16 + rowf;
            float bv = bias[gn];
            #pragma unroll
            for (int r = 0; r < 4; ++r)
                C[(size_t)(gm + r) * ldc + gn] = f2bf(acc[i][j][r] + bv);
        }
    }
}

// combine: Wqp_r = Wq @ Wp_r^T
__global__ __launch_bounds__(256) void combine_wq(
    const unsigned short* __restrict__ Wqb,
    const unsigned short* __restrict__ WpbT,
    const float* __restrict__ zbias,
    unsigned short* __restrict__ Wqpb)
{
    __shared__ unsigned short As[64][72];
    __shared__ unsigned short Bs[128][72];
    int bi = blockIdx.x;
    int r = bi >> 3, rem = bi & 7;
    int m0 = (rem >> 1) * 64, n0 = (rem & 1) * 128;
    gemm_core_64x128(As, Bs, Wqb, 256, WpbT + (size_t)r * 65536, 256, zbias,
                     Wqpb + (size_t)r * 65536, 256, 256, m0, n0);
}

// q/k/v in one launch
__global__ __launch_bounds__(256) void qkv_fused(
    const unsigned short* __restrict__ srcb,
    const unsigned short* __restrict__ Wqpb,
    const unsigned short* __restrict__ Wkb,
    const unsigned short* __restrict__ Wvb,
    const float* __restrict__ bqc, const float* __restrict__ bk,
    const float* __restrict__ bv,
    unsigned short* __restrict__ qb, unsigned short* __restrict__ kb,
    unsigned short* __restrict__ vb)
{
    __shared__ unsigned short As[64][72];
    __shared__ unsigned short Bs[128][72];
    int bi = blockIdx.x;
    const unsigned short *B;
    const float* bias;
    unsigned short* C;
    int ldb, K, m0, n0, ldc;
    if (bi < 320) {
        B = Wqpb; bias = bqc; C = qb; ldb = 256; K = 192; ldc = 1280;
        m0 = (bi / 10) * 64; n0 = (bi % 10) * 128;
    } else if (bi < 384) {
        int t = bi - 320;
        B = Wkb; bias = bk; C = kb; ldb = 192; K = 192; ldc = 256;
        m0 = (t >> 1) * 64; n0 = (t & 1) * 128;
    } else {
        int t = bi - 384;
        B = Wvb; bias = bv; C = vb; ldb = 192; K = 192; ldc = 256;
        m0 = (t >> 1) * 64; n0 = (t & 1) * 128;
    }
    gemm_core_64x128(As, Bs, srcb, KPAD, B, ldb, bias, C, ldc, K, m0, n0);
}

// ================= banded attention: 32 queries / block, 8 waves =================
__global__ __launch_bounds__(512) void attn32(
    const unsigned short* __restrict__ q,
    const unsigned short* __restrict__ k,
    const unsigned short* __restrict__ v,
    unsigned short* __restrict__ ctx, int L)
{
    __shared__ unsigned short ksm[34][264];
    __shared__ unsigned short vsm[34][264];
    const int j0 = blockIdx.x * 32;
    const int iblk0 = (j0 >= 68) ? (j0 - 64) / 5 : 0;
    int ihim = (j0 + 95) / 5; if (ihim > L - 1) ihim = L - 1;
    const int NR = ihim - iblk0 + 1;                 // <= 33

    for (int e = threadIdx.x; e < 34 * 32; e += 512) {
        int rr = e >> 5, cc = (e & 31) * 8;
        u32x4 kz = {0, 0, 0, 0}, vz = {0, 0, 0, 0};
        if (rr < NR) {
            kz = *(const u32x4*)&k[(size_t)(iblk0 + rr) * 256 + cc];
            vz = *(const u32x4*)&v[(size_t)(iblk0 + rr) * 256 + cc];
        }
        *(u32x4*)&ksm[rr][cc] = kz;
        *(u32x4*)&vsm[rr][cc] = vz;
    }
    __syncthreads();

    const int tid = threadIdx.x;
    const int wid = tid >> 6, lane = tid & 63;
    const int qq = (wid >> 2) * 16 + (lane & 15);    // 0..31
    const int h = wid & 3;
    const int p = lane >> 4;
    const int j = j0 + qq;
    const int colb = h * 64 + p * 16;

    float qr[16];
    {
        u32x4 q0 = *(const u32x4*)&q[(size_t)j * 256 + colb];
        u32x4 q1 = *(const u32x4*)&q[(size_t)j * 256 + colb + 8];
        #pragma unroll
        for (int w = 0; w < 4; ++w) {
            qr[2 * w]     = bflo(q0[w]) * 0.125f;
            qr[2 * w + 1] = bfhi(q0[w]) * 0.125f;
            qr[8 + 2 * w]     = bflo(q1[w]) * 0.125f;
            qr[8 + 2 * w + 1] = bfhi(q1[w]) * 0.125f;
        }
    }
    const int ilo = (j >= 68) ? (j - 64) / 5 : 0;
    int ihi = (j + 64) / 5; if (ihi > L - 1) ihi = L - 1;

    float sc[33];
    #pragma unroll
    for (int t = 0; t < 33; ++t) {
        int i = iblk0 + t;
        u32x4 k0 = *(const u32x4*)&ksm[t][colb];
        u32x4 k1 = *(const u32x4*)&ksm[t][colb + 8];
        float s = 0.f;
        #pragma unroll
        for (int w = 0; w < 4; ++w) {
            s += qr[2 * w]     * bflo(k0[w]);
            s += qr[2 * w + 1] * bfhi(k0[w]);
            s += qr[8 + 2 * w]     * bflo(k1[w]);
            s += qr[8 + 2 * w + 1] * bfhi(k1[w]);
        }
        s += __shfl_xor(s, 16, 64);
        s += __shfl_xor(s, 32, 64);
        sc[t] = (i >= ilo && i <= ihi) ? s : -1e30f;
    }
    float mx = -1e30f;
    #pragma unroll
    for (int t = 0; t < 33; ++t) mx = fmaxf(mx, sc[t]);
    float den = 0.f, o[16];
    #pragma unroll
    for (int d = 0; d < 16; ++d) o[d] = 0.f;
    #pragma unroll
    for (int t = 0; t < 33; ++t) {
        float pt = __expf(sc[t] - mx);
        den += pt;
        u32x4 v0 = *(const u32x4*)&vsm[t][colb];
        u32x4 v1 = *(const u32x4*)&vsm[t][colb + 8];
        #pragma unroll
        for (int w = 0; w < 4; ++w) {
            o[2 * w]     += pt * bflo(v0[w]);
            o[2 * w + 1] += pt * bfhi(v0[w]);
            o[8 + 2 * w]     += pt * bflo(v1[w]);
            o[8 + 2 * w + 1] += pt * bfhi(v1[w]);
        }
    }
    float inv = 1.f / den;
    #pragma unroll
    for (int d = 0; d < 16; ++d)
        ctx[(size_t)j * 256 + colb + d] = f2bf(o[d] * inv);
}

// ================= conv_mega: Wo-GEMM + LN + residual + skip + 4xconv + final LN ==
__device__ __forceinline__ void wload4a(u32x4 (&b)[4], const unsigned short* p) {
    asm volatile(
        "global_load_dwordx4 %0, %4, off\n\t"
        "global_load_dwordx4 %1, %4, off offset:1024\n\t"
        "global_load_dwordx4 %2, %4, off offset:2048\n\t"
        "global_load_dwordx4 %3, %4, off offset:3072"
        : "=&v"(b[0]), "=&v"(b[1]), "=&v"(b[2]), "=&v"(b[3])
        : "v"(p));
}
__device__ __forceinline__ void wwait8a(u32x4 (&b)[4]) {
    asm volatile("s_waitcnt vmcnt(8)" : "+v"(b[0]), "+v"(b[1]), "+v"(b[2]), "+v"(b[3]));
}
__device__ __forceinline__ void wwait4a(u32x4 (&b)[4]) {
    asm volatile("s_waitcnt vmcnt(4)" : "+v"(b[0]), "+v"(b[1]), "+v"(b[2]), "+v"(b[3]));
}
__device__ __forceinline__ void wwait0a(u32x4 (&b)[4]) {
    asm volatile("s_waitcnt vmcnt(0)" : "+v"(b[0]), "+v"(b[1]), "+v"(b[2]), "+v"(b[3]));
}

// DTMODE 0: conv (dt=kt>>2, cb=(kt&3)*64); 1: dt=1, cb=kt*64; 2: dt=0, cb=kt*64
template<int NKT, int DTMODE, int NROW>
__device__ __forceinline__ void frag_gemm_body(
    const unsigned short* __restrict__ base,
    const unsigned short (*actin)[264],
    f32x4 (&acc)[NROW][2], u32x4 (&W)[3][4], int lane)
{
    const int rowf = lane & 15, kq = lane >> 4;
    if (NKT > 2)      wwait8a(W[0]);
    else if (NKT > 1) wwait4a(W[0]);
    else              wwait0a(W[0]);

    #pragma unroll
    for (int kt = 0; kt < NKT; ++kt) {
        u32x4 (&cur)[4] = W[kt % 3];
        const int dt = (DTMODE == 0) ? (kt >> 2) : (DTMODE == 1 ? 1 : 0);
        const int cb = (DTMODE == 0) ? ((kt & 3) * 64) : (kt * 64);
        #pragma unroll
        for (int ks = 0; ks < 2; ++ks) {
            bf16x8 w0 = asbf(ks ? cur[1] : cur[0]);
            bf16x8 w1 = asbf(ks ? cur[3] : cur[2]);
            #pragma unroll
            for (int i = 0; i < NROW; ++i) {
                bf16x8 a = *(const bf16x8*)&actin[i * 16 + rowf + dt][cb + ks * 32 + kq * 8];
                acc[i][0] = __builtin_amdgcn_mfma_f32_16x16x32_bf16(a, w0, acc[i][0], 0, 0, 0);
                acc[i][1] = __builtin_amdgcn_mfma_f32_16x16x32_bf16(a, w1, acc[i][1], 0, 0, 0);
            }
        }
        if (kt + 3 < NKT) {
            wload4a(cur, base + (size_t)(kt + 3) * 16384);
            wwait8a(W[(kt + 1) % 3]);
        } else if (kt + 2 < NKT) {
            wwait4a(W[(kt + 1) % 3]);
        } else if (kt + 1 < NKT) {
            wwait0a(W[(kt + 1) % 3]);
        }
    }
}

template<int NKT, int DTMODE, int NROW>
__device__ __forceinline__ void frag_gemm(
    const unsigned short* __restrict__ Wp,
    const unsigned short (*actin)[264],
    f32x4 (&acc)[NROW][2], int wid, int lane)
{
    const unsigned short* base = Wp + wid * 2048 + lane * 8;
    u32x4 W[3][4];
    wload4a(W[0], base);
    if (NKT > 1) wload4a(W[1], base + 16384);
    if (NKT > 2) wload4a(W[2], base + 2 * 16384);
    frag_gemm_body<NKT, DTMODE, NROW>(base, actin, acc, W, lane);
}

__global__ __launch_bounds__(512)
__attribute__((amdgpu_waves_per_eu(2)))
void conv_mega(
    const unsigned short* __restrict__ ctx,    // (T,256) bf16
    const float* __restrict__ residual,
    const unsigned short* __restrict__ Wob,    // packed, 4 kt
    const float* __restrict__ bo,
    const unsigned short* __restrict__ Wcb,    // packed, 4 layers x 12 kt
    const float* __restrict__ conv_b,
    const unsigned short* __restrict__ Wsb,    // packed, 4 kt
    const float* __restrict__ b_skip,
    float* __restrict__ out, int T)
{
    __shared__ unsigned short actA[50][264];
    __shared__ unsigned short actB[64][264];   // also ctx staging
    __shared__ float redS[64][8];
    __shared__ float redQ[64][8];

    const int tid = threadIdx.x;
    const int lane = tid & 63;
    const int wid = tid >> 6;
    const int rowf = lane & 15;
    const int kq = lane >> 4;
    const int t0 = blockIdx.x * CVALID;
    const int gn0 = wid * 32 + rowf;

    // ---- T14: residual prefetch (issued first; lands under staging + Wo-GEMM)
    float resv[4][4][2];
    #pragma unroll
    for (int i = 0; i < 4; ++i)
        #pragma unroll
        for (int r = 0; r < 4; ++r) {
            int row = i * 16 + kq * 4 + r;
            int g = t0 - 5 + row;
            float r0 = 0.f, r1 = 0.f;
            if (row < 50 && g >= 0 && g < T) {
                const float* p = residual + (size_t)g * 256 + gn0;
                asm volatile(
                    "global_load_dword %0, %2, off\n\t"
                    "global_load_dword %1, %2, off offset:64"
                    : "=&v"(r0), "=&v"(r1) : "v"(p));
            }
            resv[i][r][0] = r0; resv[i][r][1] = r1;
        }

    // ---- T14: pre-issue Wo weight batches (land under ctx staging)
    const unsigned short* wbase0 = Wob + wid * 2048 + lane * 8;
    u32x4 WW[3][4];
    wload4a(WW[0], wbase0);
    wload4a(WW[1], wbase0 + 16384);
    wload4a(WW[2], wbase0 + 2 * 16384);

    // ---- stage ctx window (64 rows: g = t0-5+b)
    for (int e = tid; e < 64 * 32; e += 512) {
        int b = e >> 5, c = (e & 31) * 8;
        int g = t0 - 5 + b;
        u32x4 z = {0, 0, 0, 0};
        if (g >= 0 && g < T)
            z = *(const u32x4*)&ctx[(size_t)g * 256 + c];
        *(u32x4*)&actB[b][c] = z;
    }
    __syncthreads();

    // ---- attn_out tile = ctx @ Wo^T + bo (64 rows)
    f32x4 wacc[4][2];
    #pragma unroll
    for (int i = 0; i < 4; ++i)
        #pragma unroll
        for (int j = 0; j < 2; ++j) wacc[i][j] = (f32x4){0.f, 0.f, 0.f, 0.f};
    frag_gemm_body<4, 2, 4>(wbase0, actB, wacc, WW, lane);

    float bo0 = bo[gn0], bo1 = bo[gn0 + 16];
    #pragma unroll
    for (int i = 0; i < 4; ++i)
        #pragma unroll
        for (int r = 0; r < 4; ++r) {
            float a = wacc[i][0][r] + bo0;
            float b = wacc[i][1][r] + bo1;
            wacc[i][0][r] = a; wacc[i][1][r] = b;
            float s = a + b;
            float q = a * a + b * b;
            #pragma unroll
            for (int m = 1; m < 16; m <<= 1) {
                s += __shfl_xor(s, m, 64);
                q += __shfl_xor(q, m, 64);
            }
            if (rowf == 0) {
                int row = i * 16 + kq * 4 + r;
                redS[row][wid] = s;
                redQ[row][wid] = q;
            }
        }
    __syncthreads();

    // ---- ensure residual prefetch landed; tie regs so uses can't be hoisted
    asm volatile("s_waitcnt vmcnt(0)");
    #pragma unroll
    for (int i = 0; i < 4; ++i)
        asm volatile("" : "+v"(resv[i][0][0]), "+v"(resv[i][0][1]),
                          "+v"(resv[i][1][0]), "+v"(resv[i][1][1]),
                          "+v"(resv[i][2][0]), "+v"(resv[i][2][1]),
                          "+v"(resv[i][3][0]), "+v"(resv[i][3][1]));

    // ---- LN + residual -> cnn_in rows 0..49 into actA
    #pragma unroll
    for (int i = 0; i < 4; ++i)
        #pragma unroll
        for (int r = 0; r < 4; ++r) {
            int row = i * 16 + kq * 4 + r;
            if (row >= 50) continue;
            int g = t0 - 5 + row;
            float s = 0.f, q = 0.f;
            #pragma unroll
            for (int x = 0; x < 8; ++x) { s += redS[row][x]; q += redQ[row][x]; }
            float mu = s * (1.f / 256.f);
            float var = q * (1.f / 256.f) - mu * mu;
            float rs = rsqrtf(var + EPS);
            unsigned short o0 = 0, o1 = 0;
            if (g >= 0 && g < T) {
                o0 = f2bf((wacc[i][0][r] - mu) * rs + resv[i][r][0]);
                o1 = f2bf((wacc[i][1][r] - mu) * rs + resv[i][r][1]);
            }
            actA[row][gn0]      = o0;
            actA[row][gn0 + 16] = o1;
        }
    __syncthreads();

    // ---- skip GEMM (cnn_in @ W_skip^T)
    f32x4 skipacc[3][2];
    #pragma unroll
    for (int i = 0; i < 3; ++i)
        #pragma unroll
        for (int j = 0; j < 2; ++j) skipacc[i][j] = (f32x4){0.f, 0.f, 0.f, 0.f};
    frag_gemm<4, 1, 3>(Wsb, actA, skipacc, wid, lane);

    f32x4 cacc[3][2];
    // ---- conv layers, explicit ping-pong (no pointer select)
    #pragma unroll 1
    for (int l2 = 0; l2 < 2; ++l2) {
        const int le = 2 * l2;          // even layer: actA -> actB
        #pragma unroll
        for (int i = 0; i < 3; ++i)
            #pragma unroll
            for (int j = 0; j < 2; ++j) cacc[i][j] = (f32x4){0.f, 0.f, 0.f, 0.f};
        frag_gemm<12, 0, 3>(Wcb + (size_t)le * 196608, actA, cacc, wid, lane);
        {
            float b0 = conv_b[le * 256 + gn0];
            float b1 = conv_b[le * 256 + gn0 + 16];
            #pragma unroll
            for (int i = 0; i < 3; ++i)
                #pragma unroll
                for (int r = 0; r < 4; ++r) {
                    int w = i * 16 + kq * 4 + r;
                    int g = t0 - 4 + w;
                    bool ok = (g >= 0 && g < T);
                    float v0 = cacc[i][0][r] + b0;
                    float v1 = cacc[i][1][r] + b1;
                    v0 = 1.f - 2.f / (__expf(2.f * v0) + 1.f);
                    v1 = 1.f - 2.f / (__expf(2.f * v1) + 1.f);
                    actB[w + 1][gn0]      = ok ? f2bf(v0) : (unsigned short)0;
                    actB[w + 1][gn0 + 16] = ok ? f2bf(v1) : (unsigned short)0;
                }
            if (tid < 256) actB[0][tid] = 0; else actB[49][tid - 256] = 0;
            __syncthreads();
        }

        const int lo = 2 * l2 + 1;      // odd layer: actB -> actA (or final)
        #pragma unroll
        for (int i = 0; i < 3; ++i)
            #pragma unroll
            for (int j = 0; j < 2; ++j) cacc[i][j] = (f32x4){0.f, 0.f, 0.f, 0.f};
        frag_gemm<12, 0, 3>(Wcb + (size_t)lo * 196608, actB, cacc, wid, lane);
        {
            float b0 = conv_b[lo * 256 + gn0];
            float b1 = conv_b[lo * 256 + gn0 + 16];
            if (l2 == 0) {
                #pragma unroll
                for (int i = 0; i < 3; ++i)
                    #pragma unroll
                    for (int r = 0; r < 4; ++r) {
                        int w = i * 16 + kq * 4 + r;
                        int g = t0 - 4 + w;
                        bool ok = (g >= 0 && g < T);
                        float v0 = cacc[i][0][r] + b0;
                        float v1 = cacc[i][1][r] + b1;
                        v0 = 1.f - 2.f / (__expf(2.f * v0) + 1.f);
                        v1 = 1.f - 2.f / (__expf(2.f * v1) + 1.f);
                        actA[w + 1][gn0]      = ok ? f2bf(v0) : (unsigned short)0;
                        actA[w + 1][gn0 + 16] = ok ? f2bf(v1) : (unsigned short)0;
                    }
                if (tid < 256) actA[0][tid] = 0; else actA[49][tid - 256] = 0;
                __syncthreads();
            } else {
                float sb0 = b_skip[gn0], sb1 = b_skip[gn0 + 16];
                #pragma unroll
                for (int i = 0; i < 3; ++i)
                    #pragma unroll
                    for (int r = 0; r < 4; ++r) {
                        int w = i * 16 + kq * 4 + r;
                        int g = t0 - 4 + w;
                        bool ok = (g >= 0 && g < T);
                        float v0 = cacc[i][0][r] + b0;
                        float v1 = cacc[i][1][r] + b1;
                        v0 = ok ? (1.f - 2.f / (__expf(2.f * v0) + 1.f)) : 0.f;
                        v1 = ok ? (1.f - 2.f / (__expf(2.f * v1) + 1.f)) : 0.f;
                        skipacc[i][0][r] += sb0 + v0;
                        skipacc[i][1][r] += sb1 + v1;
                    }
            }
        }
    }

    // ---- final LayerNorm over valid rows
    #pragma unroll
    for (int i = 0; i < 3; ++i)
        #pragma unroll
        for (int r = 0; r < 4; ++r) {
            float a = skipacc[i][0][r], b = skipacc[i][1][r];
            float s = a + b;
            float q = a * a + b * b;
            #pragma unroll
            for (int m = 1; m < 16; m <<= 1) {
                s += __shfl_xor(s, m, 64);
                q += __shfl_xor(q, m, 64);
            }
            if (rowf == 0) {
                int row = i * 16 + kq * 4 + r;
                redS[row][wid] = s;
                redQ[row][wid] = q;
            }
        }
    __syncthreads();

    #pragma unroll
    for (int i = 0; i < 3; ++i)
        #pragma unroll
        for (int r = 0; r < 4; ++r) {
            int row = i * 16 + kq * 4 + r;
            if (row < 4 || row >= 44) continue;
            int g = t0 - 4 + row;
            if (g >= T) continue;
            float s = 0.f, q = 0.f;
            #pragma unroll
            for (int x = 0; x < 8; ++x) { s += redS[row][x]; q += redQ[row][x]; }
            float mu = s * (1.f / 256.f);
            float var = q * (1.f / 256.f) - mu * mu;
            float rs = rsqrtf(var + EPS);
            out[(size_t)g * 256 + gn0]      = (skipacc[i][0][r] - mu) * rs;
            out[(size_t)g * 256 + gn0 + 16] = (skipacc[i][1][r] - mu) * rs;
        }
}

extern "C" void kernel_launch(void* const* d_in, const int* in_sizes, int n_in,
                              void* d_out, int out_size, void* d_ws, size_t ws_size,
                              hipStream_t stream) {
    const float* input    = (const float*)d_in[0];
    const float* residual = (const float*)d_in[1];
    const float* W_proj   = (const float*)d_in[2];
    const float* b_proj   = (const float*)d_in[3];
    const float* Wq       = (const float*)d_in[4];
    const float* bq       = (const float*)d_in[5];
    const float* Wk       = (const float*)d_in[6];
    const float* bk       = (const float*)d_in[7];
    const float* Wv       = (const float*)d_in[8];
    const float* bv       = (const float*)d_in[9];
    const float* Wo       = (const float*)d_in[10];
    const float* bo       = (const float*)d_in[11];
    const float* conv_w   = (const float*)d_in[12];
    const float* conv_b   = (const float*)d_in[13];
    const float* W_skip   = (const float*)d_in[14];
    const float* b_skip   = (const float*)d_in[15];
    float* out = (float*)d_out;

    const int L = in_sizes[0] / PROJ;   // 2048
    const int T = 5 * L;                // 10240

    unsigned short* w16 = (unsigned short*)d_ws;
    size_t off = 0;
    auto alloc = [&](size_t n) { unsigned short* p = w16 + off; off += n; return p; };
    unsigned short* Wqb   = alloc(65536);
    unsigned short* Wkb   = alloc(49152);
    unsigned short* Wvb   = alloc(49152);
    unsigned short* Wob   = alloc(65536);                // packed
    unsigned short* Wsb   = alloc(65536);                // packed
    unsigned short* Wcb   = alloc(786432);               // packed
    unsigned short* WpbT  = alloc(327680);               // 5 x 256 x 256
    unsigned short* Wqpb  = alloc(327680);               // 1280 x 256
    unsigned short* srcb  = alloc((size_t)L * KPAD);
    unsigned short* tgtb  = alloc((size_t)T * 256);      // ctx
    unsigned short* qb    = alloc((size_t)T * 256);
    unsigned short* kb    = alloc((size_t)L * 256);
    unsigned short* vb    = alloc((size_t)L * 256);
    float* zbias = (float*)alloc(512);                   // 256 f32
    float* bqc   = (float*)alloc(2560);                  // 1280 f32

    // 1) prep: 81920+8192+12288+16384+98304+40960+L*24+256 = 307456 -> 1201 blocks
    prep_all<<<dim3(1201), 256, 0, stream>>>(
        W_proj, Wq, Wk, Wv, Wo, W_skip, conv_w, input, bq, b_proj,
        Wqb, Wkb, Wvb, Wob, Wsb, Wcb, WpbT, srcb, zbias, bqc, L);

    // 2) Wqp = Wq @ Wp_r^T (5 x 256x256, K=256)
    combine_wq<<<dim3(40), 256, 0, stream>>>(Wqb, WpbT, zbias, Wqpb);

    // 3) q/k/v fused (q directly from src via combined weights)
    qkv_fused<<<dim3(448), 256, 0, stream>>>(
        srcb, Wqpb, Wkb, Wvb, bqc, bk, bv, qb, kb, vb);

    // 4) attention -> ctx (32 queries per block)
    attn32<<<dim3(T / 32), 512, 0, stream>>>(qb, kb, vb, tgtb, L);

    // 5) conv_mega: Wo-GEMM + LN + residual + skip + conv stack + final LN -> out
    conv_mega<<<dim3(T / CVALID), 512, 0, stream>>>(
        tgtb, residual, Wob, bo, Wcb, conv_b, Wsb, b_skip, out, T);
}

// Round 19
// 84.578 us; speedup vs baseline: 1.0168x; 1.0168x over previous
//
#include <hip/hip_runtime.h>
#include <hip/hip_bf16.h>

#define PROJ 128
#define KPAD 192
#define EPS 1e-5f
#define CVALID 40

typedef __attribute__((ext_vector_type(4))) float f32x4;
typedef __attribute__((ext_vector_type(8))) short bf16x8;
typedef __attribute__((ext_vector_type(4))) unsigned int u32x4;

__device__ inline float bflo(unsigned u){ union{unsigned x;float f;}c; c.x = u<<16; return c.f; }
__device__ inline float bfhi(unsigned u){ union{unsigned x;float f;}c; c.x = u & 0xffff0000u; return c.f; }
__device__ inline float bf2f(unsigned short u){ union{unsigned x;float f;}c; c.x = ((unsigned)u)<<16; return c.f; }
__device__ inline unsigned short f2bf(float f){
    union{float f; unsigned u;} c; c.f = f;
    unsigned r = c.u + 0x7fff + ((c.u >> 16) & 1);
    return (unsigned short)(r >> 16);
}
__device__ __forceinline__ bf16x8 asbf(u32x4 u){ union{u32x4 a; bf16x8 b;} c; c.a = u; return c.b; }
__device__ __forceinline__ unsigned pk2(float a, float b){
    return (unsigned)f2bf(a) | ((unsigned)f2bf(b) << 16);
}

// ================= prep (x8 vectorized): conversion/packing + src + combined bias ==
__global__ __launch_bounds__(256) void prep_all(
    const float* __restrict__ W_proj, const float* __restrict__ Wq,
    const float* __restrict__ Wk, const float* __restrict__ Wv,
    const float* __restrict__ Wo, const float* __restrict__ Ws,
    const float* __restrict__ convw, const float* __restrict__ input,
    const float* __restrict__ bq, const float* __restrict__ b_proj,
    unsigned short* __restrict__ Wqb, unsigned short* __restrict__ Wkb,
    unsigned short* __restrict__ Wvb, unsigned short* __restrict__ Wob,
    unsigned short* __restrict__ Wsb, unsigned short* __restrict__ Wcb,
    unsigned short* __restrict__ WpbT, unsigned short* __restrict__ srcb,
    float* __restrict__ zbias, float* __restrict__ bqc, int L)
{
    int idx = blockIdx.x * 256 + threadIdx.x;
    if (idx < 81920) {
        int w = idx >> 6, lanei = idx & 63;
        int r = w >> 8, o = w & 255;
        const float* wrow = Wq + (size_t)o * 256;
        const float* bp = b_proj + r * 256;
        float s = 0.f;
        #pragma unroll
        for (int c = 0; c < 256; c += 64) s += wrow[c + lanei] * bp[c + lanei];
        #pragma unroll
        for (int m = 32; m > 0; m >>= 1) s += __shfl_xor(s, m, 64);
        if (lanei == 0) bqc[w] = s + bq[o];
        return;
    }
    idx -= 81920;
    if (idx < 8192) {        // Wqb copy x8
        const float* s = Wq + (size_t)idx * 8;
        *(u32x4*)&Wqb[(size_t)idx * 8] =
            (u32x4){pk2(s[0],s[1]), pk2(s[2],s[3]), pk2(s[4],s[5]), pk2(s[6],s[7])};
        return;
    }
    idx -= 8192;
    if (idx < 12288) {       // Wkb / Wvb x8
        int which = idx / 6144, t = idx % 6144;
        int r = t / 24, c0 = (t % 24) * 8;
        const float* W = which ? Wv : Wk;
        unsigned short* D = which ? Wvb : Wkb;
        u32x4 v = {0,0,0,0};
        if (c0 < 136) {
            const float* s = W + (size_t)r * 136 + c0;
            v = (u32x4){pk2(s[0],s[1]), pk2(s[2],s[3]), pk2(s[4],s[5]), pk2(s[6],s[7])};
        }
        *(u32x4*)&D[(size_t)r * 192 + c0] = v;
        return;
    }
    idx -= 12288;
    if (idx < 16384) {       // Wob / Wsb fragment-packed x8 (kt in [0,4))
        int which = idx / 8192, t = idx % 8192;
        int lane = t & 63, fr = (t >> 6) & 3, wid = (t >> 8) & 7, kt = t >> 11;
        int o = wid * 32 + (fr >> 1) * 16 + (lane & 15);
        int c = kt * 64 + (fr & 1) * 32 + (lane >> 4) * 8;
        const float* s = (which ? Ws : Wo) + (size_t)o * 256 + c;
        unsigned short* D = which ? Wsb : Wob;
        *(u32x4*)&D[(size_t)t * 8] =
            (u32x4){pk2(s[0],s[1]), pk2(s[2],s[3]), pk2(s[4],s[5]), pk2(s[6],s[7])};
        return;
    }
    idx -= 16384;
    if (idx < 98304) {       // Wcb fragment-packed x8 (ktl = l*12+kt)
        int t = idx;
        int lane = t & 63, fr = (t >> 6) & 3, wid = (t >> 8) & 7, ktl = t >> 11;
        int l = ktl / 12, kt = ktl % 12;
        int o = wid * 32 + (fr >> 1) * 16 + (lane & 15);
        int c = kt * 64 + (fr & 1) * 32 + (lane >> 4) * 8;
        int ktap = c >> 8, ci = c & 255;
        const float* s = convw + (((size_t)l * 256 + o) * 256 + ci) * 3 + ktap;
        float v[8];
        #pragma unroll
        for (int j = 0; j < 8; ++j) v[j] = s[(size_t)j * 3];
        *(u32x4*)&Wcb[(size_t)t * 8] =
            (u32x4){pk2(v[0],v[1]), pk2(v[2],v[3]), pk2(v[4],v[5]), pk2(v[6],v[7])};
        return;
    }
    idx -= 98304;
    if (idx < 40960) {       // WpbT x8 over d
        int t = idx;
        int r = t >> 13;
        int c = (t >> 5) & 255;
        int d0 = (t & 31) * 8;
        u32x4 v = {0,0,0,0};
        if (c < 136) {
            const float* s = W_proj + ((size_t)(r * 256 + d0)) * 136 + c;
            float x[8];
            #pragma unroll
            for (int j = 0; j < 8; ++j) x[j] = s[(size_t)j * 136];
            v = (u32x4){pk2(x[0],x[1]), pk2(x[2],x[3]), pk2(x[4],x[5]), pk2(x[6],x[7])};
        }
        *(u32x4*)&WpbT[(size_t)t * 8] = v;
        return;
    }
    idx -= 40960;
    if (idx < L * 24) {      // srcb x8
        int n = idx / 24, c0 = (idx % 24) * 8;
        u32x4 v = {0,0,0,0};
        if (c0 < PROJ) {
            const float* s = input + (size_t)n * PROJ + c0;
            v = (u32x4){pk2(s[0],s[1]), pk2(s[2],s[3]), pk2(s[4],s[5]), pk2(s[6],s[7])};
        } else if (c0 == PROJ) {
            float p[8];
            #pragma unroll
            for (int i = 0; i < 8; ++i) {
                int mask = (2 << i) - 1;
                p[i] = (float)(n & mask) / (float)(1 << i);
            }
            v = (u32x4){pk2(p[0],p[1]), pk2(p[2],p[3]), pk2(p[4],p[5]), pk2(p[6],p[7])};
        }
        *(u32x4*)&srcb[(size_t)n * KPAD + c0] = v;
        return;
    }
    idx -= L * 24;
    if (idx < 256) { zbias[idx] = 0.f; return; }
}

// ================= shared 64x128 GEMM core =================
__device__ __forceinline__ void gemm_core_64x128(
    unsigned short (&As)[64][72], unsigned short (&Bs)[128][72],
    const unsigned short* __restrict__ A, int lda,
    const unsigned short* __restrict__ B, int ldb,
    const float* __restrict__ bias,
    unsigned short* __restrict__ C, int ldc,
    int K, int m0, int n0)
{
    const int tid = threadIdx.x;
    const int lane = tid & 63;
    const int wid = tid >> 6;
    const int wm = wid >> 1, wn = wid & 1;

    const int ar = tid >> 2, asg = tid & 3;
    const int br = tid >> 1, bsg = tid & 1;

    const unsigned short* Ap = A + (size_t)(m0 + ar) * lda + asg * 16;
    const unsigned short* Bp = B + (size_t)(n0 + br) * ldb + bsg * 32;

    u32x4 ra0, ra1, rb0, rb1, rb2, rb3;
    auto loadregs = [&](int k0) {
        ra0 = *(const u32x4*)(Ap + k0);
        ra1 = *(const u32x4*)(Ap + k0 + 8);
        rb0 = *(const u32x4*)(Bp + k0);
        rb1 = *(const u32x4*)(Bp + k0 + 8);
        rb2 = *(const u32x4*)(Bp + k0 + 16);
        rb3 = *(const u32x4*)(Bp + k0 + 24);
    };
    auto stlds = [&]() {
        *(u32x4*)&As[ar][asg * 16]      = ra0;
        *(u32x4*)&As[ar][asg * 16 + 8]  = ra1;
        *(u32x4*)&Bs[br][bsg * 32]      = rb0;
        *(u32x4*)&Bs[br][bsg * 32 + 8]  = rb1;
        *(u32x4*)&Bs[br][bsg * 32 + 16] = rb2;
        *(u32x4*)&Bs[br][bsg * 32 + 24] = rb3;
    };

    f32x4 acc[2][4];
    #pragma unroll
    for (int i = 0; i < 2; ++i)
        #pragma unroll
        for (int j = 0; j < 4; ++j) acc[i][j] = (f32x4){0.f, 0.f, 0.f, 0.f};

    loadregs(0);
    stlds();
    __syncthreads();

    const int rowf = lane & 15, kb = lane >> 4;
    const int ktiles = K >> 6;
    for (int kt = 0; kt < ktiles; ++kt) {
        if (kt + 1 < ktiles) loadregs((kt + 1) << 6);
        #pragma unroll
        for (int ks = 0; ks < 2; ++ks) {
            bf16x8 af[2], bfr[4];
            #pragma unroll
            for (int i = 0; i < 2; ++i)
                af[i] = *(const bf16x8*)&As[wm * 32 + i * 16 + rowf][ks * 32 + kb * 8];
            #pragma unroll
            for (int j = 0; j < 4; ++j)
                bfr[j] = *(const bf16x8*)&Bs[wn * 64 + j * 16 + rowf][ks * 32 + kb * 8];
            #pragma unroll
            for (int i = 0; i < 2; ++i)
                #pragma unroll
                for (int j = 0; j < 4; ++j)
                    acc[i][j] = __builtin_amdgcn_mfma_f32_16x16x32_bf16(af[i], bfr[j], acc[i][j], 0, 0, 0);
        }
        __syncthreads();
        if (kt + 1 < ktiles) { stlds(); __syncthreads(); }
    }

    const int rq = lane >> 4;
    #pragma unroll
    for (int i = 0; i < 2; ++i) {
        int gm = m0 + wm * 32 + i * 16 + rq * 4;
        #pragma unroll
        for (int j = 0; j < 4; ++j) {
            int gn = n0 + wn * 64 + j * 16 + rowf;
            float bv = bias[gn];
            #pragma unroll
            for (int r = 0; r < 4; ++r)
                C[(size_t)(gm + r) * ldc + gn] = f2bf(acc[i][j][r] + bv);
        }
    }
}

// combine: Wqp_r = Wq @ Wp_r^T
__global__ __launch_bounds__(256) void combine_wq(
    const unsigned short* __restrict__ Wqb,
    const unsigned short* __restrict__ WpbT,
    const float* __restrict__ zbias,
    unsigned short* __restrict__ Wqpb)
{
    __shared__ unsigned short As[64][72];
    __shared__ unsigned short Bs[128][72];
    int bi = blockIdx.x;
    int r = bi >> 3, rem = bi & 7;
    int m0 = (rem >> 1) * 64, n0 = (rem & 1) * 128;
    gemm_core_64x128(As, Bs, Wqb, 256, WpbT + (size_t)r * 65536, 256, zbias,
                     Wqpb + (size_t)r * 65536, 256, 256, m0, n0);
}

// q/k/v in one launch
__global__ __launch_bounds__(256) void qkv_fused(
    const unsigned short* __restrict__ srcb,
    const unsigned short* __restrict__ Wqpb,
    const unsigned short* __restrict__ Wkb,
    const unsigned short* __restrict__ Wvb,
    const float* __restrict__ bqc, const float* __restrict__ bk,
    const float* __restrict__ bv,
    unsigned short* __restrict__ qb, unsigned short* __restrict__ kb,
    unsigned short* __restrict__ vb)
{
    __shared__ unsigned short As[64][72];
    __shared__ unsigned short Bs[128][72];
    int bi = blockIdx.x;
    const unsigned short *B;
    const float* bias;
    unsigned short* C;
    int ldb, K, m0, n0, ldc;
    if (bi < 320) {
        B = Wqpb; bias = bqc; C = qb; ldb = 256; K = 192; ldc = 1280;
        m0 = (bi / 10) * 64; n0 = (bi % 10) * 128;
    } else if (bi < 384) {
        int t = bi - 320;
        B = Wkb; bias = bk; C = kb; ldb = 192; K = 192; ldc = 256;
        m0 = (t >> 1) * 64; n0 = (t & 1) * 128;
    } else {
        int t = bi - 384;
        B = Wvb; bias = bv; C = vb; ldb = 192; K = 192; ldc = 256;
        m0 = (t >> 1) * 64; n0 = (t & 1) * 128;
    }
    gemm_core_64x128(As, Bs, srcb, KPAD, B, ldb, bias, C, ldc, K, m0, n0);
}

// ================= banded attention =================
__global__ __launch_bounds__(256) void attn16(
    const unsigned short* __restrict__ q,
    const unsigned short* __restrict__ k,
    const unsigned short* __restrict__ v,
    unsigned short* __restrict__ ctx, int L)
{
    __shared__ unsigned short ksm[30][264];
    __shared__ unsigned short vsm[30][264];
    const int j0 = blockIdx.x * 16;
    const int iblk0 = (j0 >= 68) ? (j0 - 64) / 5 : 0;
    int ihim = (j0 + 79) / 5; if (ihim > L - 1) ihim = L - 1;
    const int NR = ihim - iblk0 + 1;

    for (int e = threadIdx.x; e < 30 * 32; e += 256) {
        int rr = e >> 5, cc = (e & 31) * 8;
        u32x4 kz = {0, 0, 0, 0}, vz = {0, 0, 0, 0};
        if (rr < NR) {
            kz = *(const u32x4*)&k[(size_t)(iblk0 + rr) * 256 + cc];
            vz = *(const u32x4*)&v[(size_t)(iblk0 + rr) * 256 + cc];
        }
        *(u32x4*)&ksm[rr][cc] = kz;
        *(u32x4*)&vsm[rr][cc] = vz;
    }
    __syncthreads();

    const int tid = threadIdx.x;
    const int h = tid >> 6, lane = tid & 63;
    const int qq = lane & 15, p = lane >> 4;
    const int j = j0 + qq;
    const int colb = h * 64 + p * 16;

    float qr[16];
    {
        u32x4 q0 = *(const u32x4*)&q[(size_t)j * 256 + colb];
        u32x4 q1 = *(const u32x4*)&q[(size_t)j * 256 + colb + 8];
        #pragma unroll
        for (int w = 0; w < 4; ++w) {
            qr[2 * w]     = bflo(q0[w]) * 0.125f;
            qr[2 * w + 1] = bfhi(q0[w]) * 0.125f;
            qr[8 + 2 * w]     = bflo(q1[w]) * 0.125f;
            qr[8 + 2 * w + 1] = bfhi(q1[w]) * 0.125f;
        }
    }
    const int ilo = (j >= 68) ? (j - 64) / 5 : 0;
    int ihi = (j + 64) / 5; if (ihi > L - 1) ihi = L - 1;

    float sc[30];
    #pragma unroll
    for (int t = 0; t < 30; ++t) {
        int i = iblk0 + t;
        u32x4 k0 = *(const u32x4*)&ksm[t][colb];
        u32x4 k1 = *(const u32x4*)&ksm[t][colb + 8];
        float s = 0.f;
        #pragma unroll
        for (int w = 0; w < 4; ++w) {
            s += qr[2 * w]     * bflo(k0[w]);
            s += qr[2 * w + 1] * bfhi(k0[w]);
            s += qr[8 + 2 * w]     * bflo(k1[w]);
            s += qr[8 + 2 * w + 1] * bfhi(k1[w]);
        }
        s += __shfl_xor(s, 16, 64);
        s += __shfl_xor(s, 32, 64);
        sc[t] = (i >= ilo && i <= ihi) ? s : -1e30f;
    }
    float mx = -1e30f;
    #pragma unroll
    for (int t = 0; t < 30; ++t) mx = fmaxf(mx, sc[t]);
    float den = 0.f, o[16];
    #pragma unroll
    for (int d = 0; d < 16; ++d) o[d] = 0.f;
    #pragma unroll
    for (int t = 0; t < 30; ++t) {
        float pt = __expf(sc[t] - mx);
        den += pt;
        u32x4 v0 = *(const u32x4*)&vsm[t][colb];
        u32x4 v1 = *(const u32x4*)&vsm[t][colb + 8];
        #pragma unroll
        for (int w = 0; w < 4; ++w) {
            o[2 * w]     += pt * bflo(v0[w]);
            o[2 * w + 1] += pt * bfhi(v0[w]);
            o[8 + 2 * w]     += pt * bflo(v1[w]);
            o[8 + 2 * w + 1] += pt * bfhi(v1[w]);
        }
    }
    float inv = 1.f / den;
    #pragma unroll
    for (int d = 0; d < 16; ++d)
        ctx[(size_t)j * 256 + colb + d] = f2bf(o[d] * inv);
}

// ================= conv_mega: Wo-GEMM + LN + residual + skip + 4xconv + final LN ==
__device__ __forceinline__ void wload4a(u32x4 (&b)[4], const unsigned short* p) {
    asm volatile(
        "global_load_dwordx4 %0, %4, off\n\t"
        "global_load_dwordx4 %1, %4, off offset:1024\n\t"
        "global_load_dwordx4 %2, %4, off offset:2048\n\t"
        "global_load_dwordx4 %3, %4, off offset:3072"
        : "=&v"(b[0]), "=&v"(b[1]), "=&v"(b[2]), "=&v"(b[3])
        : "v"(p));
}
__device__ __forceinline__ void wwait8a(u32x4 (&b)[4]) {
    asm volatile("s_waitcnt vmcnt(8)" : "+v"(b[0]), "+v"(b[1]), "+v"(b[2]), "+v"(b[3]));
}
__device__ __forceinline__ void wwait4a(u32x4 (&b)[4]) {
    asm volatile("s_waitcnt vmcnt(4)" : "+v"(b[0]), "+v"(b[1]), "+v"(b[2]), "+v"(b[3]));
}
__device__ __forceinline__ void wwait0a(u32x4 (&b)[4]) {
    asm volatile("s_waitcnt vmcnt(0)" : "+v"(b[0]), "+v"(b[1]), "+v"(b[2]), "+v"(b[3]));
}

// DTMODE 0: conv (dt=kt>>2, cb=(kt&3)*64); 1: dt=1, cb=kt*64; 2: dt=0, cb=kt*64
template<int NKT, int DTMODE, int NROW>
__device__ __forceinline__ void frag_gemm_body(
    const unsigned short* __restrict__ base,
    const unsigned short (*actin)[264],
    f32x4 (&acc)[NROW][2], u32x4 (&W)[3][4], int lane)
{
    const int rowf = lane & 15, kq = lane >> 4;
    if (NKT > 2)      wwait8a(W[0]);
    else if (NKT > 1) wwait4a(W[0]);
    else              wwait0a(W[0]);

    #pragma unroll
    for (int kt = 0; kt < NKT; ++kt) {
        u32x4 (&cur)[4] = W[kt % 3];
        const int dt = (DTMODE == 0) ? (kt >> 2) : (DTMODE == 1 ? 1 : 0);
        const int cb = (DTMODE == 0) ? ((kt & 3) * 64) : (kt * 64);
        #pragma unroll
        for (int ks = 0; ks < 2; ++ks) {
            bf16x8 w0 = asbf(ks ? cur[1] : cur[0]);
            bf16x8 w1 = asbf(ks ? cur[3] : cur[2]);
            #pragma unroll
            for (int i = 0; i < NROW; ++i) {
                bf16x8 a = *(const bf16x8*)&actin[i * 16 + rowf + dt][cb + ks * 32 + kq * 8];
                acc[i][0] = __builtin_amdgcn_mfma_f32_16x16x32_bf16(a, w0, acc[i][0], 0, 0, 0);
                acc[i][1] = __builtin_amdgcn_mfma_f32_16x16x32_bf16(a, w1, acc[i][1], 0, 0, 0);
            }
        }
        if (kt + 3 < NKT) {
            wload4a(cur, base + (size_t)(kt + 3) * 16384);
            wwait8a(W[(kt + 1) % 3]);
        } else if (kt + 2 < NKT) {
            wwait4a(W[(kt + 1) % 3]);
        } else if (kt + 1 < NKT) {
            wwait0a(W[(kt + 1) % 3]);
        }
    }
}

template<int NKT, int DTMODE, int NROW>
__device__ __forceinline__ void frag_gemm(
    const unsigned short* __restrict__ Wp,
    const unsigned short (*actin)[264],
    f32x4 (&acc)[NROW][2], int wid, int lane)
{
    const unsigned short* base = Wp + wid * 2048 + lane * 8;
    u32x4 W[3][4];
    wload4a(W[0], base);
    if (NKT > 1) wload4a(W[1], base + 16384);
    if (NKT > 2) wload4a(W[2], base + 2 * 16384);
    frag_gemm_body<NKT, DTMODE, NROW>(base, actin, acc, W, lane);
}

__global__ __launch_bounds__(512)
__attribute__((amdgpu_waves_per_eu(2)))
void conv_mega(
    const unsigned short* __restrict__ ctx,    // (T,256) bf16
    const float* __restrict__ residual,
    const unsigned short* __restrict__ Wob,    // packed, 4 kt
    const float* __restrict__ bo,
    const unsigned short* __restrict__ Wcb,    // packed, 4 layers x 12 kt
    const float* __restrict__ conv_b,
    const unsigned short* __restrict__ Wsb,    // packed, 4 kt
    const float* __restrict__ b_skip,
    float* __restrict__ out, int T)
{
    __shared__ unsigned short actA[50][264];
    __shared__ unsigned short actB[64][264];   // also ctx staging
    __shared__ float redS[64][8];
    __shared__ float redQ[64][8];

    const int tid = threadIdx.x;
    const int lane = tid & 63;
    const int wid = tid >> 6;
    const int rowf = lane & 15;
    const int kq = lane >> 4;
    const int t0 = blockIdx.x * CVALID;
    const int gn0 = wid * 32 + rowf;

    // ---- T14: residual prefetch (issued first; lands under staging + Wo-GEMM)
    float resv[4][4][2];
    #pragma unroll
    for (int i = 0; i < 4; ++i)
        #pragma unroll
        for (int r = 0; r < 4; ++r) {
            int row = i * 16 + kq * 4 + r;
            int g = t0 - 5 + row;
            float r0 = 0.f, r1 = 0.f;
            if (row < 50 && g >= 0 && g < T) {
                const float* p = residual + (size_t)g * 256 + gn0;
                asm volatile(
                    "global_load_dword %0, %2, off\n\t"
                    "global_load_dword %1, %2, off offset:64"
                    : "=&v"(r0), "=&v"(r1) : "v"(p));
            }
            resv[i][r][0] = r0; resv[i][r][1] = r1;
        }

    // ---- T14: pre-issue Wo weight batches (land under ctx staging)
    const unsigned short* wbase0 = Wob + wid * 2048 + lane * 8;
    u32x4 WW[3][4];
    wload4a(WW[0], wbase0);
    wload4a(WW[1], wbase0 + 16384);
    wload4a(WW[2], wbase0 + 2 * 16384);

    // ---- stage ctx window (64 rows: g = t0-5+b)
    for (int e = tid; e < 64 * 32; e += 512) {
        int b = e >> 5, c = (e & 31) * 8;
        int g = t0 - 5 + b;
        u32x4 z = {0, 0, 0, 0};
        if (g >= 0 && g < T)
            z = *(const u32x4*)&ctx[(size_t)g * 256 + c];
        *(u32x4*)&actB[b][c] = z;
    }
    __syncthreads();

    // ---- attn_out tile = ctx @ Wo^T + bo (64 rows)
    f32x4 wacc[4][2];
    #pragma unroll
    for (int i = 0; i < 4; ++i)
        #pragma unroll
        for (int j = 0; j < 2; ++j) wacc[i][j] = (f32x4){0.f, 0.f, 0.f, 0.f};
    frag_gemm_body<4, 2, 4>(wbase0, actB, wacc, WW, lane);

    float bo0 = bo[gn0], bo1 = bo[gn0 + 16];
    #pragma unroll
    for (int i = 0; i < 4; ++i)
        #pragma unroll
        for (int r = 0; r < 4; ++r) {
            float a = wacc[i][0][r] + bo0;
            float b = wacc[i][1][r] + bo1;
            wacc[i][0][r] = a; wacc[i][1][r] = b;
            float s = a + b;
            float q = a * a + b * b;
            #pragma unroll
            for (int m = 1; m < 16; m <<= 1) {
                s += __shfl_xor(s, m, 64);
                q += __shfl_xor(q, m, 64);
            }
            if (rowf == 0) {
                int row = i * 16 + kq * 4 + r;
                redS[row][wid] = s;
                redQ[row][wid] = q;
            }
        }
    __syncthreads();

    // ---- ensure residual prefetch landed; tie regs so uses can't be hoisted
    asm volatile("s_waitcnt vmcnt(0)");
    #pragma unroll
    for (int i = 0; i < 4; ++i)
        asm volatile("" : "+v"(resv[i][0][0]), "+v"(resv[i][0][1]),
                          "+v"(resv[i][1][0]), "+v"(resv[i][1][1]),
                          "+v"(resv[i][2][0]), "+v"(resv[i][2][1]),
                          "+v"(resv[i][3][0]), "+v"(resv[i][3][1]));

    // ---- LN + residual -> cnn_in rows 0..49 into actA
    #pragma unroll
    for (int i = 0; i < 4; ++i)
        #pragma unroll
        for (int r = 0; r < 4; ++r) {
            int row = i * 16 + kq * 4 + r;
            if (row >= 50) continue;
            int g = t0 - 5 + row;
            float s = 0.f, q = 0.f;
            #pragma unroll
            for (int x = 0; x < 8; ++x) { s += redS[row][x]; q += redQ[row][x]; }
            float mu = s * (1.f / 256.f);
            float var = q * (1.f / 256.f) - mu * mu;
            float rs = rsqrtf(var + EPS);
            unsigned short o0 = 0, o1 = 0;
            if (g >= 0 && g < T) {
                o0 = f2bf((wacc[i][0][r] - mu) * rs + resv[i][r][0]);
                o1 = f2bf((wacc[i][1][r] - mu) * rs + resv[i][r][1]);
            }
            actA[row][gn0]      = o0;
            actA[row][gn0 + 16] = o1;
        }
    __syncthreads();

    // ---- skip GEMM (cnn_in @ W_skip^T)
    f32x4 skipacc[3][2];
    #pragma unroll
    for (int i = 0; i < 3; ++i)
        #pragma unroll
        for (int j = 0; j < 2; ++j) skipacc[i][j] = (f32x4){0.f, 0.f, 0.f, 0.f};
    frag_gemm<4, 1, 3>(Wsb, actA, skipacc, wid, lane);

    f32x4 cacc[3][2];
    // ---- conv layers, explicit ping-pong (no pointer select)
    #pragma unroll 1
    for (int l2 = 0; l2 < 2; ++l2) {
        const int le = 2 * l2;          // even layer: actA -> actB
        #pragma unroll
        for (int i = 0; i < 3; ++i)
            #pragma unroll
            for (int j = 0; j < 2; ++j) cacc[i][j] = (f32x4){0.f, 0.f, 0.f, 0.f};
        frag_gemm<12, 0, 3>(Wcb + (size_t)le * 196608, actA, cacc, wid, lane);
        {
            float b0 = conv_b[le * 256 + gn0];
            float b1 = conv_b[le * 256 + gn0 + 16];
            #pragma unroll
            for (int i = 0; i < 3; ++i)
                #pragma unroll
                for (int r = 0; r < 4; ++r) {
                    int w = i * 16 + kq * 4 + r;
                    int g = t0 - 4 + w;
                    bool ok = (g >= 0 && g < T);
                    float v0 = cacc[i][0][r] + b0;
                    float v1 = cacc[i][1][r] + b1;
                    v0 = 1.f - 2.f / (__expf(2.f * v0) + 1.f);
                    v1 = 1.f - 2.f / (__expf(2.f * v1) + 1.f);
                    actB[w + 1][gn0]      = ok ? f2bf(v0) : (unsigned short)0;
                    actB[w + 1][gn0 + 16] = ok ? f2bf(v1) : (unsigned short)0;
                }
            if (tid < 256) actB[0][tid] = 0; else actB[49][tid - 256] = 0;
            __syncthreads();
        }

        const int lo = 2 * l2 + 1;      // odd layer: actB -> actA (or final)
        #pragma unroll
        for (int i = 0; i < 3; ++i)
            #pragma unroll
            for (int j = 0; j < 2; ++j) cacc[i][j] = (f32x4){0.f, 0.f, 0.f, 0.f};
        frag_gemm<12, 0, 3>(Wcb + (size_t)lo * 196608, actB, cacc, wid, lane);
        {
            float b0 = conv_b[lo * 256 + gn0];
            float b1 = conv_b[lo * 256 + gn0 + 16];
            if (l2 == 0) {
                #pragma unroll
                for (int i = 0; i < 3; ++i)
                    #pragma unroll
                    for (int r = 0; r < 4; ++r) {
                        int w = i * 16 + kq * 4 + r;
                        int g = t0 - 4 + w;
                        bool ok = (g >= 0 && g < T);
                        float v0 = cacc[i][0][r] + b0;
                        float v1 = cacc[i][1][r] + b1;
                        v0 = 1.f - 2.f / (__expf(2.f * v0) + 1.f);
                        v1 = 1.f - 2.f / (__expf(2.f * v1) + 1.f);
                        actA[w + 1][gn0]      = ok ? f2bf(v0) : (unsigned short)0;
                        actA[w + 1][gn0 + 16] = ok ? f2bf(v1) : (unsigned short)0;
                    }
                if (tid < 256) actA[0][tid] = 0; else actA[49][tid - 256] = 0;
                __syncthreads();
            } else {
                float sb0 = b_skip[gn0], sb1 = b_skip[gn0 + 16];
                #pragma unroll
                for (int i = 0; i < 3; ++i)
                    #pragma unroll
                    for (int r = 0; r < 4; ++r) {
                        int w = i * 16 + kq * 4 + r;
                        int g = t0 - 4 + w;
                        bool ok = (g >= 0 && g < T);
                        float v0 = cacc[i][0][r] + b0;
                        float v1 = cacc[i][1][r] + b1;
                        v0 = ok ? (1.f - 2.f / (__expf(2.f * v0) + 1.f)) : 0.f;
                        v1 = ok ? (1.f - 2.f / (__expf(2.f * v1) + 1.f)) : 0.f;
                        skipacc[i][0][r] += sb0 + v0;
                        skipacc[i][1][r] += sb1 + v1;
                    }
            }
        }
    }

    // ---- final LayerNorm over valid rows
    #pragma unroll
    for (int i = 0; i < 3; ++i)
        #pragma unroll
        for (int r = 0; r < 4; ++r) {
            float a = skipacc[i][0][r], b = skipacc[i][1][r];
            float s = a + b;
            float q = a * a + b * b;
            #pragma unroll
            for (int m = 1; m < 16; m <<= 1) {
                s += __shfl_xor(s, m, 64);
                q += __shfl_xor(q, m, 64);
            }
            if (rowf == 0) {
                int row = i * 16 + kq * 4 + r;
                redS[row][wid] = s;
                redQ[row][wid] = q;
            }
        }
    __syncthreads();

    #pragma unroll
    for (int i = 0; i < 3; ++i)
        #pragma unroll
        for (int r = 0; r < 4; ++r) {
            int row = i * 16 + kq * 4 + r;
            if (row < 4 || row >= 44) continue;
            int g = t0 - 4 + row;
            if (g >= T) continue;
            float s = 0.f, q = 0.f;
            #pragma unroll
            for (int x = 0; x < 8; ++x) { s += redS[row][x]; q += redQ[row][x]; }
            float mu = s * (1.f / 256.f);
            float var = q * (1.f / 256.f) - mu * mu;
            float rs = rsqrtf(var + EPS);
            out[(size_t)g * 256 + gn0]      = (skipacc[i][0][r] - mu) * rs;
            out[(size_t)g * 256 + gn0 + 16] = (skipacc[i][1][r] - mu) * rs;
        }
}

extern "C" void kernel_launch(void* const* d_in, const int* in_sizes, int n_in,
                              void* d_out, int out_size, void* d_ws, size_t ws_size,
                              hipStream_t stream) {
    const float* input    = (const float*)d_in[0];
    const float* residual = (const float*)d_in[1];
    const float* W_proj   = (const float*)d_in[2];
    const float* b_proj   = (const float*)d_in[3];
    const float* Wq       = (const float*)d_in[4];
    const float* bq       = (const float*)d_in[5];
    const float* Wk       = (const float*)d_in[6];
    const float* bk       = (const float*)d_in[7];
    const float* Wv       = (const float*)d_in[8];
    const float* bv       = (const float*)d_in[9];
    const float* Wo       = (const float*)d_in[10];
    const float* bo       = (const float*)d_in[11];
    const float* conv_w   = (const float*)d_in[12];
    const float* conv_b   = (const float*)d_in[13];
    const float* W_skip   = (const float*)d_in[14];
    const float* b_skip   = (const float*)d_in[15];
    float* out = (float*)d_out;

    const int L = in_sizes[0] / PROJ;   // 2048
    const int T = 5 * L;                // 10240

    unsigned short* w16 = (unsigned short*)d_ws;
    size_t off = 0;
    auto alloc = [&](size_t n) { unsigned short* p = w16 + off; off += n; return p; };
    unsigned short* Wqb   = alloc(65536);
    unsigned short* Wkb   = alloc(49152);
    unsigned short* Wvb   = alloc(49152);
    unsigned short* Wob   = alloc(65536);                // packed
    unsigned short* Wsb   = alloc(65536);                // packed
    unsigned short* Wcb   = alloc(786432);               // packed
    unsigned short* WpbT  = alloc(327680);               // 5 x 256 x 256
    unsigned short* Wqpb  = alloc(327680);               // 1280 x 256
    unsigned short* srcb  = alloc((size_t)L * KPAD);
    unsigned short* tgtb  = alloc((size_t)T * 256);      // ctx
    unsigned short* qb    = alloc((size_t)T * 256);
    unsigned short* kb    = alloc((size_t)L * 256);
    unsigned short* vb    = alloc((size_t)L * 256);
    float* zbias = (float*)alloc(512);                   // 256 f32
    float* bqc   = (float*)alloc(2560);                  // 1280 f32

    // 1) prep: 81920+8192+12288+16384+98304+40960+L*24+256 = 307456 -> 1201 blocks
    prep_all<<<dim3(1201), 256, 0, stream>>>(
        W_proj, Wq, Wk, Wv, Wo, W_skip, conv_w, input, bq, b_proj,
        Wqb, Wkb, Wvb, Wob, Wsb, Wcb, WpbT, srcb, zbias, bqc, L);

    // 2) Wqp = Wq @ Wp_r^T (5 x 256x256, K=256)
    combine_wq<<<dim3(40), 256, 0, stream>>>(Wqb, WpbT, zbias, Wqpb);

    // 3) q/k/v fused (q directly from src via combined weights)
    qkv_fused<<<dim3(448), 256, 0, stream>>>(
        srcb, Wqpb, Wkb, Wvb, bqc, bk, bv, qb, kb, vb);

    // 4) attention -> ctx
    attn16<<<dim3(T / 16), 256, 0, stream>>>(qb, kb, vb, tgtb, L);

    // 5) conv_mega: Wo-GEMM + LN + residual + skip + conv stack + final LN -> out
    conv_mega<<<dim3(T / CVALID), 512, 0, stream>>>(
        tgtb, residual, Wob, bo, Wcb, conv_b, Wsb, b_skip, out, T);
}